// Round 5
// baseline (17504.944 us; speedup 1.0000x reference)
//
#include <hip/hip_runtime.h>
#include <hip/hip_fp16.h>

#define B_ 256
#define S_ 512
#define F_ 64
#define H_ 1024
#define O_ 24
#define G_ 4096  // 4*H

typedef _Float16 half_t;
typedef _Float16 h8 __attribute__((ext_vector_type(8)));
typedef float f4 __attribute__((ext_vector_type(4)));

// ---- workspace layout (bytes) ----
#define OFF_H1 ((size_t)0)                                   // 2*B*H halfs (ping-pong)
#define OFF_H2 (OFF_H1 + (size_t)2*B_*H_*2)
#define OFF_C1 (OFF_H2 + (size_t)2*B_*H_*2)                  // B*H f32
#define OFF_C2 (OFF_C1 + (size_t)B_*H_*4)
#define OFF_OP (OFF_C2 + (size_t)B_*H_*4)                    // out_part [32][B][O] f32
#define ZBYTES (OFF_OP + (size_t)32*B_*O_*4)
#define OFF_BIAS0 (ZBYTES)
#define OFF_BIAS1 (OFF_BIAS0 + (size_t)G_*4)
#define OFF_XH    (OFF_BIAS1 + (size_t)G_*4)                 // B*S*F halfs
#define OFF_WIH0  (OFF_XH + (size_t)B_*S_*F_*2)              // packed, G*F halfs
#define OFF_WHH0  (OFF_WIH0 + (size_t)G_*F_*2)               // packed, G*H halfs
#define OFF_WIH1  (OFF_WHH0 + (size_t)G_*H_*2)
#define OFF_WHH1  (OFF_WIH1 + (size_t)G_*H_*2)
#define WS_NEEDED (OFF_WHH1 + (size_t)G_*H_*2)               // ~47.5 MB

__global__ void k_bias(const float* __restrict__ bi0, const float* __restrict__ bh0,
                       const float* __restrict__ bi1, const float* __restrict__ bh1,
                       float* __restrict__ bias0, float* __restrict__ bias1) {
    int i = blockIdx.x * blockDim.x + threadIdx.x;
    if (i < G_) { bias0[i] = bi0[i] + bh0[i]; bias1[i] = bi1[i] + bh1[i]; }
}

__global__ void k_cvt(const float* __restrict__ src, half_t* __restrict__ dst, int n) {
    int i = blockIdx.x * blockDim.x + threadIdx.x;
    int stride = gridDim.x * blockDim.x;
    for (; i < n; i += stride) dst[i] = (half_t)src[i];
}

// Pack W [4H, NC*64] f32 -> fp16 MFMA-fragment order:
// dst h8 index i = (((g*32+ht)*NC + ck)*4 + j)*64 + lane, j = colhalf*2 + kshalf
__global__ void k_pack(const float* __restrict__ src, half_t* __restrict__ dst, int NC) {
    int i = blockIdx.x * blockDim.x + threadIdx.x;
    int total = 32768 * NC;          // 4*32*NC*4*64
    if (i >= total) return;
    int lane = i & 63;
    int j    = (i >> 6) & 3;
    int ck   = (i >> 8) % NC;
    int gh   = i / (256 * NC);       // g*32+ht, 0..127
    int srow = (gh >> 5) * H_ + (gh & 31) * 32 + (j >> 1) * 16 + (lane & 15);
    int scol = ck * 64 + (j & 1) * 32 + (lane >> 4) * 8;
    const float* s = src + (size_t)srow * (NC * 64) + scol;
    h8 v;
    #pragma unroll
    for (int e = 0; e < 8; ++e) v[e] = (half_t)s[e];
    *(h8*)&dst[(size_t)i * 8] = v;
}

// Fused phase kernel: phase t = layer0 step t (blocks 256..511) + layer1 step
// t-1 (blocks 0..255), 2 blocks/CU. Block tile 32b x 32h x 4 gates, wave=gate.
// ZERO __syncthreads in the K-loop: W comes from the packed fragment-order
// arrays (global->VGPR, coalesced 1KB/instr, L2-resident via ht%8==XCD map);
// A fragments load global->VGPR directly (4x wave redundancy served by L1).
// The barrier-before-s_barrier vmcnt(0) drain was the round-2/4 ~20 us/phase
// stall; without barriers, 8 independent waves/CU pipeline the L2 latency.
// Prefetch ping-pongs between two NAMED register sets (no copies; never a
// runtime-indexed local array — that goes to scratch: round-3's 55x cliff).
__global__ __launch_bounds__(256, 2)
void k_phase(int t,
             const half_t* __restrict__ x_h,
             const half_t* __restrict__ Wih0, const half_t* __restrict__ Whh0,
             const float* __restrict__ bias0, float* __restrict__ c1, half_t* __restrict__ h1buf,
             const half_t* __restrict__ Wih1, const half_t* __restrict__ Whh1,
             const float* __restrict__ bias1, float* __restrict__ c2, half_t* __restrict__ h2buf,
             const float* __restrict__ fcW, float* __restrict__ out_part)
{
    __shared__ float gate_s[4][32 * 33];
    __shared__ float h_s[32 * 33];

    const int n  = blockIdx.x;
    const bool l1 = (n < 256);
    const int m  = l1 ? n : n - 256;
    const int ht = (m & 7) + 8 * ((m >> 3) & 3);   // ht % 8 == linear_id % 8 (XCD-resident W)
    const int bt = (m >> 5) & 7;

    int tt; const half_t* xb; int ldx, cx; const half_t* Wih;
    const half_t* Whh; const float* bias; float* c; half_t* hn_out; const half_t* hp;
    if (l1) {
        if (t == 0) return;
        tt = t - 1;
        xb  = h1buf + (size_t)(tt & 1) * B_ * H_;  ldx = H_;      cx = 16;
        Wih = Wih1;  Whh = Whh1;  bias = bias1;  c = c2;
        hp     = h2buf + (size_t)((tt - 1) & 1) * B_ * H_;
        hn_out = h2buf + (size_t)(tt & 1) * B_ * H_;
    } else {
        if (t >= S_) return;
        tt = t;
        xb  = x_h + (size_t)tt * F_;  ldx = S_ * F_;  cx = 1;
        Wih = Wih0;  Whh = Whh0;  bias = bias0;  c = c1;
        hp     = h1buf + (size_t)((tt - 1) & 1) * B_ * H_;
        hn_out = h1buf + (size_t)(tt & 1) * B_ * H_;
    }

    const int thr  = threadIdx.x;
    const int wave = thr >> 6, lane = thr & 63;
    const int quad = lane >> 4, l15 = lane & 15;
    const int hbase = ht * 32;

    // bias folded into accumulator init (col = nt*16 + l15)
    float bv0 = bias[wave * H_ + hbase + l15];
    float bv1 = bias[wave * H_ + hbase + 16 + l15];
    f4 acc[2][2];
    #pragma unroll
    for (int mt = 0; mt < 2; ++mt) {
        acc[mt][0] = (f4){bv0, bv0, bv0, bv0};
        acc[mt][1] = (f4){bv1, bv1, bv1, bv1};
    }

    const int nchunks = cx + 16;            // K = cx*64 + 1024
    const int ghW = wave * 32 + ht;         // packed-W (gate,ht) group

    // A-fragment row/col offsets (A-operand layout: lane holds A[m=l15][k=quad*8+j])
    const int arow0 = bt * 32 + l15;
    const int arow1 = arow0 + 16;
    const int akq   = quad * 8;

    auto fetchA = [&](int ck, h8& a0, h8& a1, h8& a2, h8& a3) {
        const half_t* Ab; int lda, k0;
        if (ck < cx) { Ab = xb; lda = ldx; k0 = ck * 64; }
        else         { Ab = hp; lda = H_;  k0 = (ck - cx) * 64; }
        const half_t* r0 = Ab + (size_t)arow0 * lda + k0 + akq;
        const half_t* r1 = Ab + (size_t)arow1 * lda + k0 + akq;
        a0 = *(const h8*)(r0);
        a1 = *(const h8*)(r1);
        a2 = *(const h8*)(r0 + 32);
        a3 = *(const h8*)(r1 + 32);
    };
    auto fetchW = [&](int ck, h8& w0, h8& w1, h8& w2, h8& w3) {
        const half_t* Wb; int ckk, NC;
        if (ck < cx) { Wb = Wih; ckk = ck;      NC = cx; }
        else         { Wb = Whh; ckk = ck - cx; NC = 16; }
        const half_t* base = Wb + ((size_t)(((ghW * NC) + ckk) * 4) * 64 + lane) * 8;
        w0 = *(const h8*)(base + 0 * 512);
        w1 = *(const h8*)(base + 1 * 512);
        w2 = *(const h8*)(base + 2 * 512);
        w3 = *(const h8*)(base + 3 * 512);
    };

    h8 xa0, xa1, xa2, xa3, xw0, xw1, xw2, xw3;   // set X
    h8 ya0, ya1, ya2, ya3, yw0, yw1, yw2, yw3;   // set Y

    #define MFMA_SET(a0v,a1v,a2v,a3v,w0v,w1v,w2v,w3v)                                  \
        acc[0][0] = __builtin_amdgcn_mfma_f32_16x16x32_f16(a0v, w0v, acc[0][0], 0,0,0);\
        acc[0][1] = __builtin_amdgcn_mfma_f32_16x16x32_f16(a0v, w2v, acc[0][1], 0,0,0);\
        acc[1][0] = __builtin_amdgcn_mfma_f32_16x16x32_f16(a1v, w0v, acc[1][0], 0,0,0);\
        acc[1][1] = __builtin_amdgcn_mfma_f32_16x16x32_f16(a1v, w2v, acc[1][1], 0,0,0);\
        acc[0][0] = __builtin_amdgcn_mfma_f32_16x16x32_f16(a2v, w1v, acc[0][0], 0,0,0);\
        acc[0][1] = __builtin_amdgcn_mfma_f32_16x16x32_f16(a2v, w3v, acc[0][1], 0,0,0);\
        acc[1][0] = __builtin_amdgcn_mfma_f32_16x16x32_f16(a3v, w1v, acc[1][0], 0,0,0);\
        acc[1][1] = __builtin_amdgcn_mfma_f32_16x16x32_f16(a3v, w3v, acc[1][1], 0,0,0);

    fetchA(0, xa0, xa1, xa2, xa3);
    fetchW(0, xw0, xw1, xw2, xw3);
    const int npair = nchunks >> 1;
    for (int p = 0; p < npair; ++p) {
        const int k0 = 2 * p;
        fetchA(k0 + 1, ya0, ya1, ya2, ya3);
        fetchW(k0 + 1, yw0, yw1, yw2, yw3);
        MFMA_SET(xa0, xa1, xa2, xa3, xw0, xw1, xw2, xw3)
        const int k2 = (k0 + 2 == nchunks) ? k0 + 1 : k0 + 2;   // clamp (last even pair: dead fetch)
        fetchA(k2, xa0, xa1, xa2, xa3);
        fetchW(k2, xw0, xw1, xw2, xw3);
        MFMA_SET(ya0, ya1, ya2, ya3, yw0, yw1, yw2, yw3)
    }
    if (nchunks & 1) {   // odd tail (l0: 17 chunks) — last chunk sits in set X
        MFMA_SET(xa0, xa1, xa2, xa3, xw0, xw1, xw2, xw3)
    }
    #undef MFMA_SET

    // scatter gates (C/D layout col=lane&15, row=quad*4+reg)
    #pragma unroll
    for (int mt = 0; mt < 2; ++mt)
        #pragma unroll
        for (int nt = 0; nt < 2; ++nt)
            #pragma unroll
            for (int r = 0; r < 4; ++r)
                gate_s[wave][(mt * 16 + quad * 4 + r) * 33 + nt * 16 + l15] = acc[mt][nt][r];
    __syncthreads();

    // cell update: 1024 (b,h) elems, 4/thread
    #pragma unroll
    for (int kk = 0; kk < 4; ++kk) {
        int e = thr + kk * 256;
        int b = e >> 5, col = e & 31;
        float gi = gate_s[0][b * 33 + col];
        float gf = gate_s[1][b * 33 + col];
        float gg = gate_s[2][b * 33 + col];
        float go = gate_s[3][b * 33 + col];
        float si = 1.f / (1.f + __expf(-gi));
        float sf = 1.f / (1.f + __expf(-gf));
        float so = 1.f / (1.f + __expf(-go));
        float tg = tanhf(gg);
        size_t cidx = (size_t)(bt * 32 + b) * H_ + hbase + col;
        float cn = sf * c[cidx] + si * tg;
        c[cidx] = cn;
        float hnv = so * tanhf(cn);
        hn_out[cidx] = (half_t)hnv;
        h_s[b * 33 + col] = hnv;
    }

    if (l1) {
        __syncthreads();
        const float* fcWt = fcW + (size_t)tt * H_;
        for (int p = thr; p < 32 * O_; p += 256) {
            int o = p >> 5, bb = p & 31;
            float s = 0.f;
            #pragma unroll 8
            for (int j = 0; j < 32; ++j)
                s += h_s[bb * 33 + j] * fcWt[(size_t)o * (S_ * H_) + hbase + j];
            out_part[ht * (B_ * O_) + (bt * 32 + bb) * O_ + o] += s;
        }
    }
}

__global__ void k_final(const float* __restrict__ out_part, const float* __restrict__ fcb,
                        float* __restrict__ out) {
    int i = blockIdx.x * blockDim.x + threadIdx.x;
    if (i >= B_ * O_) return;
    int o = i % O_;
    float s = fcb[o];
    for (int t = 0; t < 32; ++t) s += out_part[t * (B_ * O_) + i];
    out[i] = s;
}

extern "C" void kernel_launch(void* const* d_in, const int* in_sizes, int n_in,
                              void* d_out, int out_size, void* d_ws, size_t ws_size,
                              hipStream_t stream) {
    const float* x    = (const float*)d_in[0];
    const float* Wih0 = (const float*)d_in[1];
    const float* Whh0 = (const float*)d_in[2];
    const float* bih0 = (const float*)d_in[3];
    const float* bhh0 = (const float*)d_in[4];
    const float* Wih1 = (const float*)d_in[5];
    const float* Whh1 = (const float*)d_in[6];
    const float* bih1 = (const float*)d_in[7];
    const float* bhh1 = (const float*)d_in[8];
    const float* fcW  = (const float*)d_in[9];
    const float* fcb  = (const float*)d_in[10];

    char* ws = (char*)d_ws;
    half_t* h1buf  = (half_t*)(ws + OFF_H1);
    half_t* h2buf  = (half_t*)(ws + OFF_H2);
    float*  c1     = (float*)(ws + OFF_C1);
    float*  c2     = (float*)(ws + OFF_C2);
    float*  opart  = (float*)(ws + OFF_OP);
    float*  bias0  = (float*)(ws + OFF_BIAS0);
    float*  bias1  = (float*)(ws + OFF_BIAS1);
    half_t* x_h    = (half_t*)(ws + OFF_XH);
    half_t* wih0_p = (half_t*)(ws + OFF_WIH0);
    half_t* whh0_p = (half_t*)(ws + OFF_WHH0);
    half_t* wih1_p = (half_t*)(ws + OFF_WIH1);
    half_t* whh1_p = (half_t*)(ws + OFF_WHH1);

    hipMemsetAsync(d_ws, 0, ZBYTES, stream);

    k_bias<<<dim3((G_ + 255) / 256), dim3(256), 0, stream>>>(bih0, bhh0, bih1, bhh1, bias0, bias1);
    k_cvt<<<dim3(2048), dim3(256), 0, stream>>>(x, x_h, B_ * S_ * F_);
    k_pack<<<dim3(128),  dim3(256), 0, stream>>>(Wih0, wih0_p, 1);
    k_pack<<<dim3(2048), dim3(256), 0, stream>>>(Whh0, whh0_p, 16);
    k_pack<<<dim3(2048), dim3(256), 0, stream>>>(Wih1, wih1_p, 16);
    k_pack<<<dim3(2048), dim3(256), 0, stream>>>(Whh1, whh1_p, 16);

    dim3 grid(512), blk(256);
    for (int t = 0; t <= S_; ++t) {
        k_phase<<<grid, blk, 0, stream>>>(t, x_h,
                                          wih0_p, whh0_p, bias0, c1, h1buf,
                                          wih1_p, whh1_p, bias1, c2, h2buf,
                                          fcW, opart);
    }
    k_final<<<dim3((B_ * O_ + 255) / 256), dim3(256), 0, stream>>>(opart, fcb, (float*)d_out);
}

// Round 6
// 12305.222 us; speedup vs baseline: 1.4226x; 1.4226x over previous
//
#include <hip/hip_runtime.h>
#include <hip/hip_fp16.h>

#define B_ 256
#define S_ 512
#define F_ 64
#define H_ 1024
#define O_ 24
#define G_ 4096  // 4*H

typedef _Float16 half_t;
typedef _Float16 h8 __attribute__((ext_vector_type(8)));
typedef float f4 __attribute__((ext_vector_type(4)));

// ---- workspace layout (bytes) ----
#define OFF_H1 ((size_t)0)                                   // 2*B*H halfs (ping-pong)
#define OFF_H2 (OFF_H1 + (size_t)2*B_*H_*2)
#define OFF_C1 (OFF_H2 + (size_t)2*B_*H_*2)                  // B*H f32
#define OFF_C2 (OFF_C1 + (size_t)B_*H_*4)
#define OFF_OP (OFF_C2 + (size_t)B_*H_*4)                    // out_part [32][B][O] f32
#define ZBYTES (OFF_OP + (size_t)32*B_*O_*4)
#define OFF_BIAS0 (ZBYTES)
#define OFF_BIAS1 (OFF_BIAS0 + (size_t)G_*4)
#define OFF_XH    (OFF_BIAS1 + (size_t)G_*4)                 // B*S*F halfs
#define OFF_WIH0  (OFF_XH + (size_t)B_*S_*F_*2)              // packed, G*F halfs
#define OFF_WHH0  (OFF_WIH0 + (size_t)G_*F_*2)               // packed, G*H halfs
#define OFF_WIH1  (OFF_WHH0 + (size_t)G_*H_*2)
#define OFF_WHH1  (OFF_WIH1 + (size_t)G_*H_*2)
#define WS_NEEDED (OFF_WHH1 + (size_t)G_*H_*2)               // ~47.5 MB

// lgkm-only barrier: __syncthreads would emit s_waitcnt vmcnt(0) before
// s_barrier, force-draining the global prefetch queue every chunk (the R4
// stall). LDS producer/consumer correctness only needs lgkmcnt(0). Keeping
// both instructions inside ONE asm block prevents the compiler from hoisting
// LDS ops between the wait and the barrier.
#define LGKM_BARRIER() asm volatile("s_waitcnt lgkmcnt(0)\ns_barrier" ::: "memory")

__global__ void k_bias(const float* __restrict__ bi0, const float* __restrict__ bh0,
                       const float* __restrict__ bi1, const float* __restrict__ bh1,
                       float* __restrict__ bias0, float* __restrict__ bias1) {
    int i = blockIdx.x * blockDim.x + threadIdx.x;
    if (i < G_) { bias0[i] = bi0[i] + bh0[i]; bias1[i] = bi1[i] + bh1[i]; }
}

__global__ void k_cvt(const float* __restrict__ src, half_t* __restrict__ dst, int n) {
    int i = blockIdx.x * blockDim.x + threadIdx.x;
    int stride = gridDim.x * blockDim.x;
    for (; i < n; i += stride) dst[i] = (half_t)src[i];
}

// Pack W [4H, NC*64] f32 -> fp16 MFMA-fragment order:
// dst h8 index i = (((g*32+ht)*NC + ck)*4 + j)*64 + lane, j = colhalf*2 + kshalf
__global__ void k_pack(const float* __restrict__ src, half_t* __restrict__ dst, int NC) {
    int i = blockIdx.x * blockDim.x + threadIdx.x;
    int total = 32768 * NC;          // 4*32*NC*4*64
    if (i >= total) return;
    int lane = i & 63;
    int j    = (i >> 6) & 3;
    int ck   = (i >> 8) % NC;
    int gh   = i / (256 * NC);       // g*32+ht, 0..127
    int srow = (gh >> 5) * H_ + (gh & 31) * 32 + (j >> 1) * 16 + (lane & 15);
    int scol = ck * 64 + (j & 1) * 32 + (lane >> 4) * 8;
    const float* s = src + (size_t)srow * (NC * 64) + scol;
    h8 v;
    #pragma unroll
    for (int e = 0; e < 8; ++e) v[e] = (half_t)s[e];
    *(h8*)&dst[(size_t)i * 8] = v;
}

// Fused phase kernel: phase t = layer0 step t (blocks 256..511) + layer1 step
// t-1 (blocks 0..255), 2 blocks/CU. Block tile 32b x 32h x 4 gates, wave=gate.
// A: cooperative LDS staging (coalesced, 1x global traffic) with DOUBLE buffer
// and ONE lgkm-only barrier per chunk -> global prefetch never drained.
// W: direct global->VGPR from packed fragment-order arrays (1KB coalesced per
// instr, L2-resident via ht%8==XCD map), ping-pong in NAMED register sets
// (runtime-indexed local arrays go to scratch: round-3's 55x cliff).
__global__ __launch_bounds__(256, 2)
void k_phase(int t,
             const half_t* __restrict__ x_h,
             const half_t* __restrict__ Wih0, const half_t* __restrict__ Whh0,
             const float* __restrict__ bias0, float* __restrict__ c1, half_t* __restrict__ h1buf,
             const half_t* __restrict__ Wih1, const half_t* __restrict__ Whh1,
             const float* __restrict__ bias1, float* __restrict__ c2, half_t* __restrict__ h2buf,
             const float* __restrict__ fcW, float* __restrict__ out_part)
{
    __shared__ __align__(16) half_t A_s[2][32 * 72];   // double-buffered A tile
    __shared__ float gate_s[4][32 * 33];
    __shared__ float h_s[32 * 33];

    const int n  = blockIdx.x;
    const bool l1 = (n < 256);
    const int m  = l1 ? n : n - 256;
    const int ht = (m & 7) + 8 * ((m >> 3) & 3);   // ht % 8 == linear_id % 8 (XCD-resident W)
    const int bt = (m >> 5) & 7;

    int tt; const half_t* xb; int ldx, cx; const half_t* Wih;
    const half_t* Whh; const float* bias; float* c; half_t* hn_out; const half_t* hp;
    if (l1) {
        if (t == 0) return;
        tt = t - 1;
        xb  = h1buf + (size_t)(tt & 1) * B_ * H_;  ldx = H_;      cx = 16;
        Wih = Wih1;  Whh = Whh1;  bias = bias1;  c = c2;
        hp     = h2buf + (size_t)((tt - 1) & 1) * B_ * H_;
        hn_out = h2buf + (size_t)(tt & 1) * B_ * H_;
    } else {
        if (t >= S_) return;
        tt = t;
        xb  = x_h + (size_t)tt * F_;  ldx = S_ * F_;  cx = 1;
        Wih = Wih0;  Whh = Whh0;  bias = bias0;  c = c1;
        hp     = h1buf + (size_t)((tt - 1) & 1) * B_ * H_;
        hn_out = h1buf + (size_t)(tt & 1) * B_ * H_;
    }

    const int thr  = threadIdx.x;
    const int wave = thr >> 6, lane = thr & 63;
    const int quad = lane >> 4, l15 = lane & 15;
    const int hbase = ht * 32;

    // bias folded into accumulator init (col = nt*16 + l15)
    float bv0 = bias[wave * H_ + hbase + l15];
    float bv1 = bias[wave * H_ + hbase + 16 + l15];
    f4 acc[2][2];
    #pragma unroll
    for (int mt = 0; mt < 2; ++mt) {
        acc[mt][0] = (f4){bv0, bv0, bv0, bv0};
        acc[mt][1] = (f4){bv1, bv1, bv1, bv1};
    }

    const int nchunks = cx + 16;            // K = cx*64 + 1024
    const int ghW = wave * 32 + ht;         // packed-W (gate,ht) group
    const int ar  = thr >> 3;               // A staging row 0..31
    const int ak  = (thr & 7) * 8;          // A staging k-offset

    f4 pA;                                  // A staging prefetch (16B/thread)
    h8 xw0, xw1, xw2, xw3;                  // W set X
    h8 yw0, yw1, yw2, yw3;                  // W set Y

    auto fetchA = [&](int ck) {
        const half_t* Ab; int lda, k0;
        if (ck < cx) { Ab = xb; lda = ldx; k0 = ck * 64; }
        else         { Ab = hp; lda = H_;  k0 = (ck - cx) * 64; }
        pA = *(const f4*)&Ab[(size_t)(bt * 32 + ar) * lda + k0 + ak];
    };
    auto fetchW = [&](int ck, h8& w0, h8& w1, h8& w2, h8& w3) {
        const half_t* Wb; int ckk, NC;
        if (ck < cx) { Wb = Wih; ckk = ck;      NC = cx; }
        else         { Wb = Whh; ckk = ck - cx; NC = 16; }
        const half_t* base = Wb + ((size_t)(((ghW * NC) + ckk) * 4) * 64 + lane) * 8;
        w0 = *(const h8*)(base + 0 * 512);
        w1 = *(const h8*)(base + 1 * 512);
        w2 = *(const h8*)(base + 2 * 512);
        w3 = *(const h8*)(base + 3 * 512);
    };

    #define MFMA_BUF(buf, w0v,w1v,w2v,w3v) {                                            \
        h8 a0 = *(const h8*)&A_s[buf][(0  + l15) * 72 + 0  + quad * 8];                 \
        h8 a1 = *(const h8*)&A_s[buf][(16 + l15) * 72 + 0  + quad * 8];                 \
        h8 a2 = *(const h8*)&A_s[buf][(0  + l15) * 72 + 32 + quad * 8];                 \
        h8 a3 = *(const h8*)&A_s[buf][(16 + l15) * 72 + 32 + quad * 8];                 \
        acc[0][0] = __builtin_amdgcn_mfma_f32_16x16x32_f16(a0, w0v, acc[0][0], 0,0,0);  \
        acc[0][1] = __builtin_amdgcn_mfma_f32_16x16x32_f16(a0, w2v, acc[0][1], 0,0,0);  \
        acc[1][0] = __builtin_amdgcn_mfma_f32_16x16x32_f16(a1, w0v, acc[1][0], 0,0,0);  \
        acc[1][1] = __builtin_amdgcn_mfma_f32_16x16x32_f16(a1, w2v, acc[1][1], 0,0,0);  \
        acc[0][0] = __builtin_amdgcn_mfma_f32_16x16x32_f16(a2, w1v, acc[0][0], 0,0,0);  \
        acc[0][1] = __builtin_amdgcn_mfma_f32_16x16x32_f16(a2, w3v, acc[0][1], 0,0,0);  \
        acc[1][0] = __builtin_amdgcn_mfma_f32_16x16x32_f16(a3, w1v, acc[1][0], 0,0,0);  \
        acc[1][1] = __builtin_amdgcn_mfma_f32_16x16x32_f16(a3, w3v, acc[1][1], 0,0,0);  \
    }

    // Pipeline: iter k does [ds_write A(k) | lgkm-barrier | issue fetch(k+1) |
    // MFMA A(k),W(k)]. Double-buffered A_s: readers of buf are 2 iters behind
    // the next write, separated by the intervening barrier. Global loads cross
    // the barrier un-drained; consumed with fine vmcnt waits one chunk later.
    fetchA(0);
    fetchW(0, xw0, xw1, xw2, xw3);
    const int npair = nchunks >> 1;
    for (int p = 0; p < npair; ++p) {
        const int k0 = 2 * p;
        // chunk k0 (even) in buf0, W in X; prefetch k0+1 into Y
        *(f4*)&A_s[0][ar * 72 + ak] = pA;
        LGKM_BARRIER();
        fetchA(k0 + 1);
        fetchW(k0 + 1, yw0, yw1, yw2, yw3);
        MFMA_BUF(0, xw0, xw1, xw2, xw3)
        // chunk k0+1 (odd) in buf1, W in Y; prefetch k0+2 into X (clamped dead fetch on last pair)
        *(f4*)&A_s[1][ar * 72 + ak] = pA;
        LGKM_BARRIER();
        const int k2 = (k0 + 2 < nchunks) ? k0 + 2 : nchunks - 1;
        fetchA(k2);
        fetchW(k2, xw0, xw1, xw2, xw3);
        MFMA_BUF(1, yw0, yw1, yw2, yw3)
    }
    if (nchunks & 1) {   // odd tail (l0: 17 chunks) — last chunk sits in pA/X
        *(f4*)&A_s[0][ar * 72 + ak] = pA;
        LGKM_BARRIER();
        MFMA_BUF(0, xw0, xw1, xw2, xw3)
    }
    #undef MFMA_BUF

    __syncthreads();   // full barrier before LDS reuse for gate exchange

    // scatter gates (C/D layout col=lane&15, row=quad*4+reg)
    #pragma unroll
    for (int mt = 0; mt < 2; ++mt)
        #pragma unroll
        for (int nt = 0; nt < 2; ++nt)
            #pragma unroll
            for (int r = 0; r < 4; ++r)
                gate_s[wave][(mt * 16 + quad * 4 + r) * 33 + nt * 16 + l15] = acc[mt][nt][r];
    __syncthreads();

    // cell update: 1024 (b,h) elems, 4/thread
    #pragma unroll
    for (int kk = 0; kk < 4; ++kk) {
        int e = thr + kk * 256;
        int b = e >> 5, col = e & 31;
        float gi = gate_s[0][b * 33 + col];
        float gf = gate_s[1][b * 33 + col];
        float gg = gate_s[2][b * 33 + col];
        float go = gate_s[3][b * 33 + col];
        float si = 1.f / (1.f + __expf(-gi));
        float sf = 1.f / (1.f + __expf(-gf));
        float so = 1.f / (1.f + __expf(-go));
        float tg = tanhf(gg);
        size_t cidx = (size_t)(bt * 32 + b) * H_ + hbase + col;
        float cn = sf * c[cidx] + si * tg;
        c[cidx] = cn;
        float hnv = so * tanhf(cn);
        hn_out[cidx] = (half_t)hnv;
        h_s[b * 33 + col] = hnv;
    }

    if (l1) {
        __syncthreads();
        const float* fcWt = fcW + (size_t)tt * H_;
        for (int p = thr; p < 32 * O_; p += 256) {
            int o = p >> 5, bb = p & 31;
            float s = 0.f;
            #pragma unroll 8
            for (int j = 0; j < 32; ++j)
                s += h_s[bb * 33 + j] * fcWt[(size_t)o * (S_ * H_) + hbase + j];
            out_part[ht * (B_ * O_) + (bt * 32 + bb) * O_ + o] += s;
        }
    }
}

__global__ void k_final(const float* __restrict__ out_part, const float* __restrict__ fcb,
                        float* __restrict__ out) {
    int i = blockIdx.x * blockDim.x + threadIdx.x;
    if (i >= B_ * O_) return;
    int o = i % O_;
    float s = fcb[o];
    for (int t = 0; t < 32; ++t) s += out_part[t * (B_ * O_) + i];
    out[i] = s;
}

extern "C" void kernel_launch(void* const* d_in, const int* in_sizes, int n_in,
                              void* d_out, int out_size, void* d_ws, size_t ws_size,
                              hipStream_t stream) {
    const float* x    = (const float*)d_in[0];
    const float* Wih0 = (const float*)d_in[1];
    const float* Whh0 = (const float*)d_in[2];
    const float* bih0 = (const float*)d_in[3];
    const float* bhh0 = (const float*)d_in[4];
    const float* Wih1 = (const float*)d_in[5];
    const float* Whh1 = (const float*)d_in[6];
    const float* bih1 = (const float*)d_in[7];
    const float* bhh1 = (const float*)d_in[8];
    const float* fcW  = (const float*)d_in[9];
    const float* fcb  = (const float*)d_in[10];

    char* ws = (char*)d_ws;
    half_t* h1buf  = (half_t*)(ws + OFF_H1);
    half_t* h2buf  = (half_t*)(ws + OFF_H2);
    float*  c1     = (float*)(ws + OFF_C1);
    float*  c2     = (float*)(ws + OFF_C2);
    float*  opart  = (float*)(ws + OFF_OP);
    float*  bias0  = (float*)(ws + OFF_BIAS0);
    float*  bias1  = (float*)(ws + OFF_BIAS1);
    half_t* x_h    = (half_t*)(ws + OFF_XH);
    half_t* wih0_p = (half_t*)(ws + OFF_WIH0);
    half_t* whh0_p = (half_t*)(ws + OFF_WHH0);
    half_t* wih1_p = (half_t*)(ws + OFF_WIH1);
    half_t* whh1_p = (half_t*)(ws + OFF_WHH1);

    hipMemsetAsync(d_ws, 0, ZBYTES, stream);

    k_bias<<<dim3((G_ + 255) / 256), dim3(256), 0, stream>>>(bih0, bhh0, bih1, bhh1, bias0, bias1);
    k_cvt<<<dim3(2048), dim3(256), 0, stream>>>(x, x_h, B_ * S_ * F_);
    k_pack<<<dim3(128),  dim3(256), 0, stream>>>(Wih0, wih0_p, 1);
    k_pack<<<dim3(2048), dim3(256), 0, stream>>>(Whh0, whh0_p, 16);
    k_pack<<<dim3(2048), dim3(256), 0, stream>>>(Wih1, wih1_p, 16);
    k_pack<<<dim3(2048), dim3(256), 0, stream>>>(Whh1, whh1_p, 16);

    dim3 grid(512), blk(256);
    for (int t = 0; t <= S_; ++t) {
        k_phase<<<grid, blk, 0, stream>>>(t, x_h,
                                          wih0_p, whh0_p, bias0, c1, h1buf,
                                          wih1_p, whh1_p, bias1, c2, h2buf,
                                          fcW, opart);
    }
    k_final<<<dim3((B_ * O_ + 255) / 256), dim3(256), 0, stream>>>(opart, fcb, (float*)d_out);
}